// Round 5
// baseline (825.408 us; speedup 1.0000x reference)
//
#include <hip/hip_runtime.h>
#include <hip/hip_bf16.h>
#include <math.h>

typedef __hip_bfloat16 bf16;
typedef short bf16x8 __attribute__((ext_vector_type(8)));
typedef float f32x4 __attribute__((ext_vector_type(4)));
typedef unsigned int u32;
typedef unsigned short u16;

#define GLD16(g, l)                                                            \
  __builtin_amdgcn_global_load_lds(                                            \
      (const __attribute__((address_space(1))) void*)(g),                      \
      (__attribute__((address_space(3))) void*)(l), 16, 0, 0)

// ------------------------------------------------------- f32 -> bf16 copy
__global__ void convert_f32_bf16(const float* __restrict__ in,
                                 bf16* __restrict__ out) {
  size_t i = ((size_t)blockIdx.x * 256 + threadIdx.x) * 4;
  float4 v = *(const float4*)(in + i);
  out[i + 0] = __float2bfloat16(v.x);
  out[i + 1] = __float2bfloat16(v.y);
  out[i + 2] = __float2bfloat16(v.z);
  out[i + 3] = __float2bfloat16(v.w);
}

// ----------------------------------------- f32 -> bf16 transposed weights
__global__ void transpose_f32_bf16(const float* __restrict__ in,
                                   bf16* __restrict__ out, int R, int C) {
  __shared__ bf16 tile[32][33];
  int tx = threadIdx.x & 31, ty = threadIdx.x >> 5;
  int c0 = blockIdx.x * 32, r0 = blockIdx.y * 32;
#pragma unroll
  for (int i = 0; i < 32; i += 8)
    tile[ty + i][tx] = __float2bfloat16(in[(size_t)(r0 + ty + i) * C + c0 + tx]);
  __syncthreads();
#pragma unroll
  for (int i = 0; i < 32; i += 8)
    out[(size_t)(c0 + ty + i) * R + r0 + tx] = tile[tx][ty + i];
}

// V: [4096][1024] bf16 (row = b*2048+t, col = kvh*128+d) -> VT: [16][128][2048]
__global__ void transpose_v(const bf16* __restrict__ V, bf16* __restrict__ VT) {
  __shared__ bf16 tile[32][33];
  int s = blockIdx.z, b = s >> 3, kvh = s & 7;
  int t0 = blockIdx.x * 32, d0 = blockIdx.y * 32;
  int tx = threadIdx.x & 31, ty = threadIdx.x >> 5;
#pragma unroll
  for (int i = 0; i < 32; i += 8)
    tile[ty + i][tx] = V[(size_t)(b * 2048 + t0 + ty + i) * 1024 + kvh * 128 + d0 + tx];
  __syncthreads();
#pragma unroll
  for (int i = 0; i < 32; i += 8)
    VT[((size_t)s * 128 + d0 + ty + i) * 2048 + t0 + tx] = tile[tx][ty + i];
}

// ---------------------------------------------------------------- RoPE
__global__ void rope_table_k(float* __restrict__ tab) {
  int idx = blockIdx.x * 256 + threadIdx.x;  // t*64 + i
  int t = idx >> 6, i = idx & 63;
  float theta = powf(10000.0f, -2.0f * (float)i / 128.0f);
  float ang = (float)t * theta;
  tab[idx * 2 + 0] = cosf(ang);
  tab[idx * 2 + 1] = sinf(ang);
}

// omul: extra output scale (1/sqrt(d) folded into Q so attention skips it)
__global__ void rope_apply(bf16* __restrict__ X, const float* __restrict__ tab,
                           int nheads, float omul) {
  size_t idx = (size_t)blockIdx.x * 256 + threadIdx.x;
  int i = (int)(idx & 63);
  size_t rest = idx >> 6;
  int h = (int)(rest % nheads);
  size_t r = rest / nheads;
  int t = (int)(r & 2047);
  float c = tab[(t * 64 + i) * 2 + 0];
  float s = tab[(t * 64 + i) * 2 + 1];
  bf16* p = X + r * ((size_t)nheads * 128) + h * 128 + 2 * i;
  float xr = __bfloat162float(p[0]), xi = __bfloat162float(p[1]);
  p[0] = __float2bfloat16((xr * c - xi * s) * omul);
  p[1] = __float2bfloat16((xr * s + xi * c) * omul);
}

// ------------------------------------------------ GEMM v1 (B^T), 128x128
// kept for the narrow K/V projections (N=1024 -> 256 blocks fills the chip)
template <typename OutT>
__global__ __launch_bounds__(256, 3) void gemm_bt(const bf16* __restrict__ A,
                                                  const bf16* __restrict__ BT,
                                                  OutT* __restrict__ C, int M,
                                                  int N, int K) {
  __shared__ bf16 As[128 * 32];
  __shared__ bf16 Bs[128 * 32];
  const int tid = threadIdx.x;
  const int lane = tid & 63, w = tid >> 6;
  const int wr = w >> 1, wc = w & 1;
  const int lr = lane & 15;
  const int ko = (lane >> 4) * 8;
  const int m0 = blockIdx.y * 128, n0 = blockIdx.x * 128;

  f32x4 acc[4][4];
#pragma unroll
  for (int m = 0; m < 4; ++m)
#pragma unroll
    for (int n = 0; n < 4; ++n)
#pragma unroll
      for (int j = 0; j < 4; ++j) acc[m][n][j] = 0.f;

  for (int k0 = 0; k0 < K; k0 += 32) {
#pragma unroll
    for (int i = 0; i < 2; ++i) {
      int c = i * 256 + tid;
      const bf16* ga = A + (size_t)(m0 + (c >> 2)) * K + k0 + (c & 3) * 8;
      const bf16* gb = BT + (size_t)(n0 + (c >> 2)) * K + k0 + (c & 3) * 8;
      GLD16(ga, As + c * 8);
      GLD16(gb, Bs + c * 8);
    }
    __syncthreads();
    bf16x8 af[4], bfr[4];
#pragma unroll
    for (int m = 0; m < 4; ++m)
      af[m] = *(const bf16x8*)(As + (wr * 64 + m * 16 + lr) * 32 + ko);
#pragma unroll
    for (int n = 0; n < 4; ++n)
      bfr[n] = *(const bf16x8*)(Bs + (wc * 64 + n * 16 + lr) * 32 + ko);
#pragma unroll
    for (int m = 0; m < 4; ++m)
#pragma unroll
      for (int n = 0; n < 4; ++n)
        acc[m][n] = __builtin_amdgcn_mfma_f32_16x16x32_bf16(af[m], bfr[n],
                                                            acc[m][n], 0, 0, 0);
    __syncthreads();
  }
#pragma unroll
  for (int m = 0; m < 4; ++m) {
    int row_base = m0 + wr * 64 + m * 16 + (lane >> 4) * 4;
#pragma unroll
    for (int n = 0; n < 4; ++n) {
      int col = n0 + wc * 64 + n * 16 + lr;
#pragma unroll
      for (int j = 0; j < 4; ++j) {
        float v = acc[m][n][j];
        if constexpr (sizeof(OutT) == 2)
          C[(size_t)(row_base + j) * N + col] = (OutT)__float2bfloat16(v);
        else
          C[(size_t)(row_base + j) * N + col] = (OutT)v;
      }
    }
  }
}

// ------------------------------------------------ GEMM v2: 128x256, BK=64,
// 8 waves, TRIPLE-buffered LDS, counted vmcnt (T3/T4), T2 swizzle, setprio.
// Loads for tile t+2 stay in flight across the barrier (vmcnt(6), never 0
// in steady state). M%128==0, N%256==0, K%64==0, K>=128.
template <typename OutT>
__global__ __launch_bounds__(512, 2) void gemm_bt2(const bf16* __restrict__ A,
                                                   const bf16* __restrict__ BT,
                                                   OutT* __restrict__ C, int M,
                                                   int N, int K) {
  __shared__ bf16 As[3][128 * 64];  // 48 KB
  __shared__ bf16 Bs[3][256 * 64];  // 96 KB
  const int tid = threadIdx.x;
  const int lane = tid & 63, w = tid >> 6;
  const int wm = w >> 2, wn = w & 3;  // 2 x 4 waves, each 64x64 out
  const int lr = lane & 15, hi = lane >> 4;
  const int m0 = blockIdx.y * 128, n0 = blockIdx.x * 256;
  const int NT = K >> 6;

  f32x4 acc[4][4];
#pragma unroll
  for (int m = 0; m < 4; ++m)
#pragma unroll
    for (int n = 0; n < 4; ++n)
#pragma unroll
      for (int j = 0; j < 4; ++j) acc[m][n][j] = 0.f;

  // stage: LDS linear dest, inverse-swizzled global source (c ^= row&7)
  auto STAGE = [&](int buf, int t) {
    const bf16* ga = A + (size_t)m0 * K + t * 64;
    const bf16* gb = BT + (size_t)n0 * K + t * 64;
#pragma unroll
    for (int it = 0; it < 2; ++it) {  // A: 128 rows x 8 chunks
      int s = it * 512 + tid;
      int row = s >> 3, c = s & 7;
      GLD16(ga + (size_t)row * K + ((c ^ (row & 7)) << 3), &As[buf][s * 8]);
    }
#pragma unroll
    for (int it = 0; it < 4; ++it) {  // B: 256 rows x 8 chunks
      int s = it * 512 + tid;
      int row = s >> 3, c = s & 7;
      GLD16(gb + (size_t)row * K + ((c ^ (row & 7)) << 3), &Bs[buf][s * 8]);
    }
  };

  STAGE(0, 0);
  STAGE(1, 1);
  asm volatile("s_waitcnt vmcnt(6)" ::: "memory");  // tile 0 landed
  __builtin_amdgcn_s_barrier();

  int cur = 0;
  for (int t = 0; t < NT; ++t) {
    int pre = cur + 2;
    if (pre >= 3) pre -= 3;
    bool more = (t + 2 < NT);
    if (more) STAGE(pre, t + 2);

    bf16x8 af[4][2], bfr[4][2];
#pragma unroll
    for (int m = 0; m < 4; ++m) {
      int row = wm * 64 + m * 16 + lr;
#pragma unroll
      for (int kk = 0; kk < 2; ++kk)
        af[m][kk] = *(const bf16x8*)(&As[cur][row * 64 +
                                             (((kk * 4 + hi) ^ (row & 7)) << 3)]);
    }
#pragma unroll
    for (int n = 0; n < 4; ++n) {
      int row = wn * 64 + n * 16 + lr;
#pragma unroll
      for (int kk = 0; kk < 2; ++kk)
        bfr[n][kk] = *(const bf16x8*)(&Bs[cur][row * 64 +
                                              (((kk * 4 + hi) ^ (row & 7)) << 3)]);
    }
    __builtin_amdgcn_s_setprio(1);
#pragma unroll
    for (int m = 0; m < 4; ++m)
#pragma unroll
      for (int n = 0; n < 4; ++n)
#pragma unroll
        for (int kk = 0; kk < 2; ++kk)
          acc[m][n] = __builtin_amdgcn_mfma_f32_16x16x32_bf16(
              af[m][kk], bfr[n][kk], acc[m][n], 0, 0, 0);
    __builtin_amdgcn_s_setprio(0);

    if (more)
      asm volatile("s_waitcnt vmcnt(6)" ::: "memory");  // t+1 landed, t+2 in flight
    else
      asm volatile("s_waitcnt vmcnt(0)" ::: "memory");  // drain (epilogue)
    __builtin_amdgcn_s_barrier();
    cur = (cur == 2) ? 0 : cur + 1;
  }

#pragma unroll
  for (int m = 0; m < 4; ++m) {
    int row_base = m0 + wm * 64 + m * 16 + hi * 4;
#pragma unroll
    for (int n = 0; n < 4; ++n) {
      int col = n0 + wn * 64 + n * 16 + lr;
#pragma unroll
      for (int j = 0; j < 4; ++j) {
        float v = acc[m][n][j];
        if constexpr (sizeof(OutT) == 2)
          C[(size_t)(row_base + j) * N + col] = (OutT)__float2bfloat16(v);
        else
          C[(size_t)(row_base + j) * N + col] = (OutT)v;
      }
    }
  }
}

// ---------------------------------------------------------------- flash attn v2
// 128 q-rows/block (4 waves x 32), KVBLK=64, dbuf LDS K/VT (XOR-swizzled),
// swapped QK^T and PV (lane <-> q-row), P in registers via pack+shfl.
// Q pre-scaled by 1/sqrt(d); defer-max (T13, THR=8); setprio (T5).
static __device__ inline u32 pack2_bf16(float a, float b) {
  u16 ua = __bfloat16_as_ushort(__float2bfloat16(a));
  u16 ub = __bfloat16_as_ushort(__float2bfloat16(b));
  return (u32)ua | ((u32)ub << 16);
}

__global__ __launch_bounds__(256) void flash_attn2(const bf16* __restrict__ Q,
                                                   const bf16* __restrict__ K,
                                                   const bf16* __restrict__ VT,
                                                   bf16* __restrict__ AO) {
  __shared__ bf16 Kbuf[2][64 * 128];   // [t][d], row stride 128 (swizzled)
  __shared__ bf16 Vbuf[2][128 * 64];   // [d][t], row stride 64 (swizzled)

  int bid = blockIdx.x;
  int lid = (bid & 7) * 128 + (bid >> 3);  // XCD-chunked swizzle (1024 % 8 == 0)
  int qt = 15 - (lid & 15);                // heavy tiles dispatch first
  int hq = (lid >> 4) & 3;
  int kvh = (lid >> 6) & 7;
  int b = lid >> 9;
  int h = kvh * 4 + hq;

  const int tid = threadIdx.x;
  const int lane = tid & 63, w = tid >> 6;
  const int lr = lane & 15, hi = lane >> 4;
  const int ko = hi * 8;
  const int qrow0 = qt * 128 + w * 32;
  const int nt = 2 * qt + 2;

  const bf16* Kg0 = K + (size_t)b * 2048 * 1024 + kvh * 128;
  const bf16* Vg0 = VT + (size_t)(b * 8 + kvh) * 128 * 2048;

  bf16x8 qf[2][4];
#pragma unroll
  for (int mi = 0; mi < 2; ++mi) {
    const bf16* qb = Q + (size_t)(b * 2048 + qrow0 + mi * 16 + lr) * 4096 + h * 128;
#pragma unroll
    for (int kk = 0; kk < 4; ++kk) qf[mi][kk] = *(const bf16x8*)(qb + kk * 32 + ko);
  }

  f32x4 O[2][8];
  float m_[2], l_[2];
#pragma unroll
  for (int mi = 0; mi < 2; ++mi) {
    m_[mi] = -1e30f;
    l_[mi] = 0.f;
#pragma unroll
    for (int dd = 0; dd < 8; ++dd)
#pragma unroll
      for (int j = 0; j < 4; ++j) O[mi][dd][j] = 0.f;
  }

  auto STAGE = [&](int buf, int kv0) {
    bf16* Ks = &Kbuf[buf][0];
    bf16* Vs = &Vbuf[buf][0];
    const bf16* Kg = Kg0 + (size_t)kv0 * 1024;
    const bf16* Vg = Vg0 + kv0;
#pragma unroll
    for (int it = 0; it < 4; ++it) {  // K: 64 rows x 16 chunks of 16B
      int s = it * 256 + tid;
      int row = s >> 4, c = s & 15;
      GLD16(Kg + (size_t)row * 1024 + ((c ^ (row & 7)) << 3), Ks + s * 8);
    }
#pragma unroll
    for (int it = 0; it < 4; ++it) {  // VT: 128 rows x 8 chunks of 16B
      int s = it * 256 + tid;
      int row = s >> 3, c = s & 7;
      GLD16(Vg + (size_t)row * 2048 + ((c ^ (row & 7)) << 3), Vs + s * 8);
    }
  };

  STAGE(0, 0);
  __syncthreads();

  for (int t = 0; t < nt; ++t) {
    int kv0 = t * 64;
    if (t + 1 < nt) STAGE((t + 1) & 1, kv0 + 64);

    if (kv0 <= qrow0 + 31) {
      const bf16* Ks = &Kbuf[t & 1][0];
      const bf16* Vs = &Vbuf[t & 1][0];

      // ---- S^T = K . Q^T : lane <-> q = qrow0+mi*16+lr, elems k = cb*16+hi*4+j
      f32x4 Sx[2][4];
#pragma unroll
      for (int mi = 0; mi < 2; ++mi)
#pragma unroll
        for (int cb = 0; cb < 4; ++cb)
#pragma unroll
          for (int j = 0; j < 4; ++j) Sx[mi][cb][j] = 0.f;

      __builtin_amdgcn_s_setprio(1);
#pragma unroll
      for (int cb = 0; cb < 4; ++cb) {
        bf16x8 kf[4];
#pragma unroll
        for (int kk = 0; kk < 4; ++kk)
          kf[kk] = *(const bf16x8*)(Ks + (cb * 16 + lr) * 128 +
                                    (((kk * 4 + hi) ^ (lr & 7)) << 3));
#pragma unroll
        for (int mi = 0; mi < 2; ++mi)
#pragma unroll
          for (int kk = 0; kk < 4; ++kk)
            Sx[mi][cb] = __builtin_amdgcn_mfma_f32_16x16x32_bf16(
                kf[kk], qf[mi][kk], Sx[mi][cb], 0, 0, 0);
      }
      __builtin_amdgcn_s_setprio(0);

      bool domask = (kv0 + 63 > qrow0);
      u32 pau[2][2][4];  // [mi][kk2][e]
#pragma unroll
      for (int mi = 0; mi < 2; ++mi) {
        int q = qrow0 + mi * 16 + lr;
        if (domask) {
#pragma unroll
          for (int cb = 0; cb < 4; ++cb)
#pragma unroll
            for (int j = 0; j < 4; ++j)
              if (kv0 + cb * 16 + hi * 4 + j > q) Sx[mi][cb][j] = -1e30f;
        }
        float pm = -1e30f;
#pragma unroll
        for (int cb = 0; cb < 4; ++cb)
#pragma unroll
          for (int j = 0; j < 4; ++j) pm = fmaxf(pm, Sx[mi][cb][j]);
        pm = fmaxf(pm, __shfl_xor(pm, 16));
        pm = fmaxf(pm, __shfl_xor(pm, 32));

        // defer-max (T13): only rescale when the running max grew by > 8
        if (!__all(pm - m_[mi] <= 8.0f)) {
          float nm = fmaxf(m_[mi], pm);
          float rs = __expf(m_[mi] - nm);
          m_[mi] = nm;
          l_[mi] *= rs;
#pragma unroll
          for (int dd = 0; dd < 8; ++dd)
#pragma unroll
            for (int j = 0; j < 4; ++j) O[mi][dd][j] *= rs;
        }
        float mcur = m_[mi];
        float ps = 0.f;
#pragma unroll
        for (int cb = 0; cb < 4; ++cb)
#pragma unroll
          for (int j = 0; j < 4; ++j) {
            float p = __expf(Sx[mi][cb][j] - mcur);
            Sx[mi][cb][j] = p;
            ps += p;
          }
        ps += __shfl_xor(ps, 16);
        ps += __shfl_xor(ps, 32);
        l_[mi] += ps;

        // pack P to bf16 pairs: vp[cb*2+jp] holds k = cb*16+hi*4+{2jp,2jp+1}
        u32 vp[8];
#pragma unroll
        for (int cb = 0; cb < 4; ++cb)
#pragma unroll
          for (int jp = 0; jp < 2; ++jp)
            vp[cb * 2 + jp] = pack2_bf16(Sx[mi][cb][2 * jp], Sx[mi][cb][2 * jp + 1]);

        // redistribute: shuffle both candidates, select at the destination
#pragma unroll
        for (int kk2 = 0; kk2 < 2; ++kk2)
#pragma unroll
          for (int e = 0; e < 4; ++e) {
            int src = lr + ((hi & 1) << 5) + ((e >> 1) << 4);
            u32 va = (u32)__shfl((int)vp[4 * kk2 + (e & 1)], src);
            u32 vb = (u32)__shfl((int)vp[4 * kk2 + 2 + (e & 1)], src);
            pau[mi][kk2][e] = (hi & 2) ? vb : va;
          }
      }

      // ---- O^T += VT . P^T : lane <-> q, rows d = dd*16+hi*4+j
      __builtin_amdgcn_s_setprio(1);
#pragma unroll
      for (int dd = 0; dd < 8; ++dd) {
        bf16x8 vf[2];
#pragma unroll
        for (int kk2 = 0; kk2 < 2; ++kk2)
          vf[kk2] = *(const bf16x8*)(Vs + (dd * 16 + lr) * 64 +
                                     (((kk2 * 4 + hi) ^ (lr & 7)) << 3));
#pragma unroll
        for (int mi = 0; mi < 2; ++mi)
#pragma unroll
          for (int kk2 = 0; kk2 < 2; ++kk2) {
            union { u32 u[4]; bf16x8 h; } cv;
#pragma unroll
            for (int e = 0; e < 4; ++e) cv.u[e] = pau[mi][kk2][e];
            O[mi][dd] = __builtin_amdgcn_mfma_f32_16x16x32_bf16(
                vf[kk2], cv.h, O[mi][dd], 0, 0, 0);
          }
      }
      __builtin_amdgcn_s_setprio(0);
    }
    __syncthreads();
  }

  // epilogue: AO[q][h*128 + d], 8B packed stores
#pragma unroll
  for (int mi = 0; mi < 2; ++mi) {
    float inv = 1.0f / l_[mi];
    bf16* outp = AO + (size_t)(b * 2048 + qrow0 + mi * 16 + lr) * 4096 + h * 128;
#pragma unroll
    for (int dd = 0; dd < 8; ++dd) {
      union { u16 s[4]; unsigned long long v; } pk;
#pragma unroll
      for (int j = 0; j < 4; ++j)
        pk.s[j] = __bfloat16_as_ushort(__float2bfloat16(O[mi][dd][j] * inv));
      *(unsigned long long*)(outp + dd * 16 + hi * 4) = pk.v;
    }
  }
}

// ---------------------------------------------------------------- launch
extern "C" void kernel_launch(void* const* d_in, const int* in_sizes, int n_in,
                              void* d_out, int out_size, void* d_ws,
                              size_t ws_size, hipStream_t stream) {
  const float* x = (const float*)d_in[0];
  const float* wq = (const float*)d_in[1];
  const float* wk = (const float*)d_in[2];
  const float* wv = (const float*)d_in[3];
  const float* wo = (const float*)d_in[4];

  char* ws = (char*)d_ws;
  bf16* xb  = (bf16*)(ws + 0);           // 32 MB — reused as AOb
  bf16* WqT = (bf16*)(ws + 33554432);    // 32 MB
  bf16* WkT = (bf16*)(ws + 67108864);    //  8 MB
  bf16* WvT = (bf16*)(ws + 75497472);    //  8 MB
  bf16* WoT = (bf16*)(ws + 83886080);    // 32 MB
  bf16* Qb  = (bf16*)(ws + 117440512);   // 32 MB
  bf16* Kb  = (bf16*)(ws + 150994944);   //  8 MB
  bf16* Vb  = (bf16*)(ws + 159383552);   //  8 MB
  bf16* VTb = (bf16*)(ws + 167772160);   //  8 MB (16x128x2048)
  float* tab = (float*)(ws + 176160768); //  1 MB
  bf16* AOb = xb;

  convert_f32_bf16<<<16384, 256, 0, stream>>>(x, xb);
  transpose_f32_bf16<<<dim3(128, 128), 256, 0, stream>>>(wq, WqT, 4096, 4096);
  transpose_f32_bf16<<<dim3(32, 128), 256, 0, stream>>>(wk, WkT, 4096, 1024);
  transpose_f32_bf16<<<dim3(32, 128), 256, 0, stream>>>(wv, WvT, 4096, 1024);
  transpose_f32_bf16<<<dim3(128, 128), 256, 0, stream>>>(wo, WoT, 4096, 4096);
  rope_table_k<<<512, 256, 0, stream>>>(tab);

  gemm_bt2<bf16><<<dim3(16, 32), 512, 0, stream>>>(xb, WqT, Qb, 4096, 4096, 4096);
  gemm_bt<bf16><<<dim3(8, 32), 256, 0, stream>>>(xb, WkT, Kb, 4096, 1024, 4096);
  gemm_bt<bf16><<<dim3(8, 32), 256, 0, stream>>>(xb, WvT, Vb, 4096, 1024, 4096);

  rope_apply<<<32768, 256, 0, stream>>>(Qb, tab, 32, 0.08838834764831845f);
  rope_apply<<<8192, 256, 0, stream>>>(Kb, tab, 8, 1.0f);

  transpose_v<<<dim3(64, 4, 16), 256, 0, stream>>>(Vb, VTb);

  flash_attn2<<<1024, 256, 0, stream>>>(Qb, Kb, VTb, AOb);

  gemm_bt2<float><<<dim3(16, 32), 512, 0, stream>>>(AOb, WoT, (float*)d_out,
                                                    4096, 4096, 4096);
}

// Round 6
// 718.236 us; speedup vs baseline: 1.1492x; 1.1492x over previous
//
#include <hip/hip_runtime.h>
#include <hip/hip_bf16.h>
#include <math.h>

typedef __hip_bfloat16 bf16;
typedef short bf16x8 __attribute__((ext_vector_type(8)));
typedef float f32x4 __attribute__((ext_vector_type(4)));
typedef unsigned int u32;
typedef unsigned short u16;

#define GLD16(g, l)                                                            \
  __builtin_amdgcn_global_load_lds(                                            \
      (const __attribute__((address_space(1))) void*)(g),                      \
      (__attribute__((address_space(3))) void*)(l), 16, 0, 0)

// ------------------------------------------------------- f32 -> bf16 copy
__global__ void convert_f32_bf16(const float* __restrict__ in,
                                 bf16* __restrict__ out) {
  size_t i = ((size_t)blockIdx.x * 256 + threadIdx.x) * 4;
  float4 v = *(const float4*)(in + i);
  out[i + 0] = __float2bfloat16(v.x);
  out[i + 1] = __float2bfloat16(v.y);
  out[i + 2] = __float2bfloat16(v.z);
  out[i + 3] = __float2bfloat16(v.w);
}

// ----------------------------------------- f32 -> bf16 transposed weights
__global__ void transpose_f32_bf16(const float* __restrict__ in,
                                   bf16* __restrict__ out, int R, int C) {
  __shared__ bf16 tile[32][33];
  int tx = threadIdx.x & 31, ty = threadIdx.x >> 5;
  int c0 = blockIdx.x * 32, r0 = blockIdx.y * 32;
#pragma unroll
  for (int i = 0; i < 32; i += 8)
    tile[ty + i][tx] = __float2bfloat16(in[(size_t)(r0 + ty + i) * C + c0 + tx]);
  __syncthreads();
#pragma unroll
  for (int i = 0; i < 32; i += 8)
    out[(size_t)(c0 + ty + i) * R + r0 + tx] = tile[tx][ty + i];
}

// V block of QKV: [4096][6144] (V at col offset, head cols kvh*128+d)
// -> VT: [16][128][2048]
__global__ void transpose_v(const bf16* __restrict__ V, bf16* __restrict__ VT) {
  __shared__ bf16 tile[32][33];
  int s = blockIdx.z, b = s >> 3, kvh = s & 7;
  int t0 = blockIdx.x * 32, d0 = blockIdx.y * 32;
  int tx = threadIdx.x & 31, ty = threadIdx.x >> 5;
#pragma unroll
  for (int i = 0; i < 32; i += 8)
    tile[ty + i][tx] =
        V[(size_t)(b * 2048 + t0 + ty + i) * 6144 + kvh * 128 + d0 + tx];
  __syncthreads();
#pragma unroll
  for (int i = 0; i < 32; i += 8)
    VT[((size_t)s * 128 + d0 + ty + i) * 2048 + t0 + tx] = tile[tx][ty + i];
}

// ---------------------------------------------------------------- RoPE
__global__ void rope_table_k(float* __restrict__ tab) {
  int idx = blockIdx.x * 256 + threadIdx.x;  // t*64 + i
  int t = idx >> 6, i = idx & 63;
  float theta = powf(10000.0f, -2.0f * (float)i / 128.0f);
  float ang = (float)t * theta;
  tab[idx * 2 + 0] = cosf(ang);
  tab[idx * 2 + 1] = sinf(ang);
}

// omul: extra output scale (log2e/sqrt(d) folded into Q for exp2-softmax)
__global__ void rope_apply(bf16* __restrict__ X, const float* __restrict__ tab,
                           int nheads, int rowstride, float omul) {
  size_t idx = (size_t)blockIdx.x * 256 + threadIdx.x;
  int i = (int)(idx & 63);
  size_t rest = idx >> 6;
  int h = (int)(rest % nheads);
  size_t r = rest / nheads;
  int t = (int)(r & 2047);
  float c = tab[(t * 64 + i) * 2 + 0];
  float s = tab[(t * 64 + i) * 2 + 1];
  bf16* p = X + r * (size_t)rowstride + h * 128 + 2 * i;
  float xr = __bfloat162float(p[0]), xi = __bfloat162float(p[1]);
  p[0] = __float2bfloat16((xr * c - xi * s) * omul);
  p[1] = __float2bfloat16((xr * s + xi * c) * omul);
}

// ------------------------------------------------ GEMM (B^T), 128x128 (m97)
// C[M][N] = A[M][K] * BT[N][K]^T ; M,N % 128 == 0, K % 32 == 0
template <typename OutT>
__global__ __launch_bounds__(256, 3) void gemm_bt(const bf16* __restrict__ A,
                                                  const bf16* __restrict__ BT,
                                                  OutT* __restrict__ C, int M,
                                                  int N, int K) {
  __shared__ bf16 As[128 * 32];
  __shared__ bf16 Bs[128 * 32];
  const int tid = threadIdx.x;
  const int lane = tid & 63, w = tid >> 6;
  const int wr = w >> 1, wc = w & 1;
  const int lr = lane & 15;
  const int ko = (lane >> 4) * 8;
  const int m0 = blockIdx.y * 128, n0 = blockIdx.x * 128;

  f32x4 acc[4][4];
#pragma unroll
  for (int m = 0; m < 4; ++m)
#pragma unroll
    for (int n = 0; n < 4; ++n)
#pragma unroll
      for (int j = 0; j < 4; ++j) acc[m][n][j] = 0.f;

  for (int k0 = 0; k0 < K; k0 += 32) {
#pragma unroll
    for (int i = 0; i < 2; ++i) {
      int c = i * 256 + tid;
      const bf16* ga = A + (size_t)(m0 + (c >> 2)) * K + k0 + (c & 3) * 8;
      const bf16* gb = BT + (size_t)(n0 + (c >> 2)) * K + k0 + (c & 3) * 8;
      GLD16(ga, As + c * 8);
      GLD16(gb, Bs + c * 8);
    }
    __syncthreads();
    bf16x8 af[4], bfr[4];
#pragma unroll
    for (int m = 0; m < 4; ++m)
      af[m] = *(const bf16x8*)(As + (wr * 64 + m * 16 + lr) * 32 + ko);
#pragma unroll
    for (int n = 0; n < 4; ++n)
      bfr[n] = *(const bf16x8*)(Bs + (wc * 64 + n * 16 + lr) * 32 + ko);
#pragma unroll
    for (int m = 0; m < 4; ++m)
#pragma unroll
      for (int n = 0; n < 4; ++n)
        acc[m][n] = __builtin_amdgcn_mfma_f32_16x16x32_bf16(af[m], bfr[n],
                                                            acc[m][n], 0, 0, 0);
    __syncthreads();
  }
#pragma unroll
  for (int m = 0; m < 4; ++m) {
    int row_base = m0 + wr * 64 + m * 16 + (lane >> 4) * 4;
#pragma unroll
    for (int n = 0; n < 4; ++n) {
      int col = n0 + wc * 64 + n * 16 + lr;
#pragma unroll
      for (int j = 0; j < 4; ++j) {
        float v = acc[m][n][j];
        if constexpr (sizeof(OutT) == 2)
          C[(size_t)(row_base + j) * N + col] = (OutT)__float2bfloat16(v);
        else
          C[(size_t)(row_base + j) * N + col] = (OutT)v;
      }
    }
  }
}

// ---------------------------------------------------------------- flash attn
// 128 q-rows/block (4 waves x 32), KVBLK=64, dbuf LDS K/VT (XOR-swizzled),
// swapped QK^T and PV (lane <-> q-row), P in regs via cvt_pk + shfl.
// Q pre-scaled by log2e/sqrt(d) -> exp2 softmax; defer-max (T13); setprio (T5).
// Q,K live inside QKV [4096][6144]: Q = QKV, K = QKV + 4096 (col offset).
static __device__ inline u32 cvtpk_bf16(float a, float b) {
  u32 r;
  asm("v_cvt_pk_bf16_f32 %0, %1, %2" : "=v"(r) : "v"(a), "v"(b));
  return r;  // lo = bf16(a), hi = bf16(b)
}

__global__ __launch_bounds__(256) void flash_attn2(const bf16* __restrict__ Q,
                                                   const bf16* __restrict__ K,
                                                   const bf16* __restrict__ VT,
                                                   bf16* __restrict__ AO) {
  __shared__ bf16 Kbuf[2][64 * 128];   // [t][d], row stride 128B*? (swizzled)
  __shared__ bf16 Vbuf[2][128 * 64];   // [d][t] (swizzled)

  int bid = blockIdx.x;
  int lid = (bid & 7) * 128 + (bid >> 3);  // XCD-chunked swizzle (1024%8==0)
  int qt = 15 - (lid & 15);                // heavy tiles dispatch first
  int hq = (lid >> 4) & 3;
  int kvh = (lid >> 6) & 7;
  int b = lid >> 9;
  int h = kvh * 4 + hq;

  const int tid = threadIdx.x;
  const int lane = tid & 63, w = tid >> 6;
  const int lr = lane & 15, hi = lane >> 4;
  const int ko = hi * 8;
  const int qrow0 = qt * 128 + w * 32;
  const int nt = 2 * qt + 2;

  const bf16* Kg0 = K + (size_t)b * 2048 * 6144 + kvh * 128;
  const bf16* Vg0 = VT + (size_t)(b * 8 + kvh) * 128 * 2048;

  bf16x8 qf[2][4];
#pragma unroll
  for (int mi = 0; mi < 2; ++mi) {
    const bf16* qb = Q + (size_t)(b * 2048 + qrow0 + mi * 16 + lr) * 6144 + h * 128;
#pragma unroll
    for (int kk = 0; kk < 4; ++kk) qf[mi][kk] = *(const bf16x8*)(qb + kk * 32 + ko);
  }

  f32x4 O[2][8];
  float m_[2], l_[2];
#pragma unroll
  for (int mi = 0; mi < 2; ++mi) {
    m_[mi] = -1e30f;
    l_[mi] = 0.f;
#pragma unroll
    for (int dd = 0; dd < 8; ++dd)
#pragma unroll
      for (int j = 0; j < 4; ++j) O[mi][dd][j] = 0.f;
  }

  auto STAGE = [&](int buf, int kv0) {
    bf16* Ks = &Kbuf[buf][0];
    bf16* Vs = &Vbuf[buf][0];
    const bf16* Kg = Kg0 + (size_t)kv0 * 6144;
    const bf16* Vg = Vg0 + kv0;
#pragma unroll
    for (int it = 0; it < 4; ++it) {  // K: 64 rows x 16 chunks of 16B
      int s = it * 256 + tid;
      int row = s >> 4, c = s & 15;
      GLD16(Kg + (size_t)row * 6144 + ((c ^ (row & 7)) << 3), Ks + s * 8);
    }
#pragma unroll
    for (int it = 0; it < 4; ++it) {  // VT: 128 rows x 8 chunks of 16B
      int s = it * 256 + tid;
      int row = s >> 3, c = s & 7;
      GLD16(Vg + (size_t)row * 2048 + ((c ^ (row & 7)) << 3), Vs + s * 8);
    }
  };

  STAGE(0, 0);
  __syncthreads();

  for (int t = 0; t < nt; ++t) {
    int kv0 = t * 64;
    if (t + 1 < nt) STAGE((t + 1) & 1, kv0 + 64);

    if (kv0 <= qrow0 + 31) {
      const bf16* Ks = &Kbuf[t & 1][0];
      const bf16* Vs = &Vbuf[t & 1][0];

      // ---- S^T = K . Q^T : lane <-> q = qrow0+mi*16+lr, elems k = cb*16+hi*4+j
      f32x4 Sx[2][4];
#pragma unroll
      for (int mi = 0; mi < 2; ++mi)
#pragma unroll
        for (int cb = 0; cb < 4; ++cb)
#pragma unroll
          for (int j = 0; j < 4; ++j) Sx[mi][cb][j] = 0.f;

      __builtin_amdgcn_s_setprio(1);
#pragma unroll
      for (int cb = 0; cb < 4; ++cb) {
        bf16x8 kf[4];
#pragma unroll
        for (int kk = 0; kk < 4; ++kk)
          kf[kk] = *(const bf16x8*)(Ks + (cb * 16 + lr) * 128 +
                                    (((kk * 4 + hi) ^ (lr & 7)) << 3));
#pragma unroll
        for (int mi = 0; mi < 2; ++mi)
#pragma unroll
          for (int kk = 0; kk < 4; ++kk)
            Sx[mi][cb] = __builtin_amdgcn_mfma_f32_16x16x32_bf16(
                kf[kk], qf[mi][kk], Sx[mi][cb], 0, 0, 0);
      }
      __builtin_amdgcn_s_setprio(0);

      bool domask = (kv0 + 63 > qrow0);
      u32 pau[2][2][4];  // [mi][kk2][e]
#pragma unroll
      for (int mi = 0; mi < 2; ++mi) {
        int q = qrow0 + mi * 16 + lr;
        if (domask) {
#pragma unroll
          for (int cb = 0; cb < 4; ++cb)
#pragma unroll
            for (int j = 0; j < 4; ++j)
              if (kv0 + cb * 16 + hi * 4 + j > q) Sx[mi][cb][j] = -1e30f;
        }
        float pm = -1e30f;
#pragma unroll
        for (int cb = 0; cb < 4; ++cb)
#pragma unroll
          for (int j = 0; j < 4; ++j) pm = fmaxf(pm, Sx[mi][cb][j]);
        pm = fmaxf(pm, __shfl_xor(pm, 16));
        pm = fmaxf(pm, __shfl_xor(pm, 32));

        // defer-max (T13): rescale only when max grew by > 8*log2e
        if (!__all(pm - m_[mi] <= 11.5416f)) {
          float nm = fmaxf(m_[mi], pm);
          float rs = exp2f(m_[mi] - nm);
          m_[mi] = nm;
          l_[mi] *= rs;
#pragma unroll
          for (int dd = 0; dd < 8; ++dd)
#pragma unroll
            for (int j = 0; j < 4; ++j) O[mi][dd][j] *= rs;
        }
        float mcur = m_[mi];
        float ps = 0.f;
#pragma unroll
        for (int cb = 0; cb < 4; ++cb)
#pragma unroll
          for (int j = 0; j < 4; ++j) {
            float p = exp2f(Sx[mi][cb][j] - mcur);
            Sx[mi][cb][j] = p;
            ps += p;
          }
        ps += __shfl_xor(ps, 16);
        ps += __shfl_xor(ps, 32);
        l_[mi] += ps;

        // pack P to bf16 pairs: vp[cb*2+jp] holds k = cb*16+hi*4+{2jp,2jp+1}
        u32 vp[8];
#pragma unroll
        for (int cb = 0; cb < 4; ++cb)
#pragma unroll
          for (int jp = 0; jp < 2; ++jp)
            vp[cb * 2 + jp] = cvtpk_bf16(Sx[mi][cb][2 * jp], Sx[mi][cb][2 * jp + 1]);

        // redistribute: shuffle both candidates, select at the destination
#pragma unroll
        for (int kk2 = 0; kk2 < 2; ++kk2)
#pragma unroll
          for (int e = 0; e < 4; ++e) {
            int src = lr + ((hi & 1) << 5) + ((e >> 1) << 4);
            u32 va = (u32)__shfl((int)vp[4 * kk2 + (e & 1)], src);
            u32 vb = (u32)__shfl((int)vp[4 * kk2 + 2 + (e & 1)], src);
            pau[mi][kk2][e] = (hi & 2) ? vb : va;
          }
      }

      // ---- O^T += VT . P^T : lane <-> q, rows d = dd*16+hi*4+j
      __builtin_amdgcn_s_setprio(1);
#pragma unroll
      for (int dd = 0; dd < 8; ++dd) {
        bf16x8 vf[2];
#pragma unroll
        for (int kk2 = 0; kk2 < 2; ++kk2)
          vf[kk2] = *(const bf16x8*)(Vs + (dd * 16 + lr) * 64 +
                                     (((kk2 * 4 + hi) ^ (lr & 7)) << 3));
#pragma unroll
        for (int mi = 0; mi < 2; ++mi)
#pragma unroll
          for (int kk2 = 0; kk2 < 2; ++kk2) {
            union { u32 u[4]; bf16x8 h; } cv;
#pragma unroll
            for (int e = 0; e < 4; ++e) cv.u[e] = pau[mi][kk2][e];
            O[mi][dd] = __builtin_amdgcn_mfma_f32_16x16x32_bf16(
                vf[kk2], cv.h, O[mi][dd], 0, 0, 0);
          }
      }
      __builtin_amdgcn_s_setprio(0);
    }
    __syncthreads();
  }

  // epilogue: AO[q][h*128 + d], 8B packed stores
#pragma unroll
  for (int mi = 0; mi < 2; ++mi) {
    float inv = 1.0f / l_[mi];
    bf16* outp = AO + (size_t)(b * 2048 + qrow0 + mi * 16 + lr) * 4096 + h * 128;
#pragma unroll
    for (int dd = 0; dd < 8; ++dd) {
      union { u16 s[4]; unsigned long long v; } pk;
#pragma unroll
      for (int j = 0; j < 4; ++j)
        pk.s[j] = __bfloat16_as_ushort(__float2bfloat16(O[mi][dd][j] * inv));
      *(unsigned long long*)(outp + dd * 16 + hi * 4) = pk.v;
    }
  }
}

// ---------------------------------------------------------------- launch
extern "C" void kernel_launch(void* const* d_in, const int* in_sizes, int n_in,
                              void* d_out, int out_size, void* d_ws,
                              size_t ws_size, hipStream_t stream) {
  const float* x = (const float*)d_in[0];
  const float* wq = (const float*)d_in[1];
  const float* wk = (const float*)d_in[2];
  const float* wv = (const float*)d_in[3];
  const float* wo = (const float*)d_in[4];

  char* ws = (char*)d_ws;
  bf16* xb    = (bf16*)(ws + 0);           // 32 MB (4096x4096) — reused as AOb
  bf16* WqkvT = (bf16*)(ws + 33554432);    // 48 MB (6144x4096: wq|wk|wv ^T)
  bf16* WoT   = (bf16*)(ws + 83886080);    // 32 MB (4096x4096)
  bf16* QKV   = (bf16*)(ws + 117440512);   // 48 MB (4096x6144)
  bf16* VTb   = (bf16*)(ws + 167772160);   //  8 MB (16x128x2048)
  float* tab  = (float*)(ws + 176160768);  //  1 MB (2048x64x2 f32)
  bf16* AOb   = xb;  // alias: x dead after QKV projection

  const float LOG2E = 1.4426950408889634f;
  const float ISQ = 0.08838834764831845f;  // 1/sqrt(128)

  convert_f32_bf16<<<16384, 256, 0, stream>>>(x, xb);
  transpose_f32_bf16<<<dim3(128, 128), 256, 0, stream>>>(wq, WqkvT, 4096, 4096);
  transpose_f32_bf16<<<dim3(32, 128), 256, 0, stream>>>(
      wk, WqkvT + (size_t)4096 * 4096, 4096, 1024);
  transpose_f32_bf16<<<dim3(32, 128), 256, 0, stream>>>(
      wv, WqkvT + (size_t)5120 * 4096, 4096, 1024);
  transpose_f32_bf16<<<dim3(128, 128), 256, 0, stream>>>(wo, WoT, 4096, 4096);
  rope_table_k<<<512, 256, 0, stream>>>(tab);

  // fused QKV projection: [4096][4096] x [6144][4096]^T -> [4096][6144]
  gemm_bt<bf16><<<dim3(48, 32), 256, 0, stream>>>(xb, WqkvT, QKV, 4096, 6144,
                                                  4096);

  rope_apply<<<32768, 256, 0, stream>>>(QKV, tab, 32, 6144, LOG2E * ISQ);
  rope_apply<<<8192, 256, 0, stream>>>(QKV + 4096, tab, 8, 6144, 1.0f);

  transpose_v<<<dim3(64, 4, 16), 256, 0, stream>>>(QKV + 5120, VTb);

  flash_attn2<<<1024, 256, 0, stream>>>(QKV, QKV + 4096, VTb, AOb);

  gemm_bt<float><<<dim3(32, 32), 256, 0, stream>>>(AOb, WoT, (float*)d_out,
                                                   4096, 4096, 4096);
}

// Round 7
// 667.063 us; speedup vs baseline: 1.2374x; 1.0767x over previous
//
#include <hip/hip_runtime.h>
#include <hip/hip_bf16.h>
#include <math.h>

typedef __hip_bfloat16 bf16;
typedef short bf16x8 __attribute__((ext_vector_type(8)));
typedef float f32x4 __attribute__((ext_vector_type(4)));
typedef unsigned int u32;
typedef unsigned short u16;

#define GLD16(g, l)                                                            \
  __builtin_amdgcn_global_load_lds(                                            \
      (const __attribute__((address_space(1))) void*)(g),                      \
      (__attribute__((address_space(3))) void*)(l), 16, 0, 0)

#define BARRIER() asm volatile("s_barrier" ::: "memory")
#define VMCNT(n) asm volatile("s_waitcnt vmcnt(" #n ")" ::: "memory")

// ------------------------------------------------------- f32 -> bf16 copy
__global__ void convert_f32_bf16(const float* __restrict__ in,
                                 bf16* __restrict__ out) {
  size_t i = ((size_t)blockIdx.x * 256 + threadIdx.x) * 4;
  float4 v = *(const float4*)(in + i);
  out[i + 0] = __float2bfloat16(v.x);
  out[i + 1] = __float2bfloat16(v.y);
  out[i + 2] = __float2bfloat16(v.z);
  out[i + 3] = __float2bfloat16(v.w);
}

// ----------------------------------------- f32 -> bf16 transposed weights
__global__ void transpose_f32_bf16(const float* __restrict__ in,
                                   bf16* __restrict__ out, int R, int C) {
  __shared__ bf16 tile[32][33];
  int tx = threadIdx.x & 31, ty = threadIdx.x >> 5;
  int c0 = blockIdx.x * 32, r0 = blockIdx.y * 32;
#pragma unroll
  for (int i = 0; i < 32; i += 8)
    tile[ty + i][tx] = __float2bfloat16(in[(size_t)(r0 + ty + i) * C + c0 + tx]);
  __syncthreads();
#pragma unroll
  for (int i = 0; i < 32; i += 8)
    out[(size_t)(c0 + ty + i) * R + r0 + tx] = tile[tx][ty + i];
}

// V block of QKV: [4096][6144] -> VT: [16][128][2048]
__global__ void transpose_v(const bf16* __restrict__ V, bf16* __restrict__ VT) {
  __shared__ bf16 tile[32][33];
  int s = blockIdx.z, b = s >> 3, kvh = s & 7;
  int t0 = blockIdx.x * 32, d0 = blockIdx.y * 32;
  int tx = threadIdx.x & 31, ty = threadIdx.x >> 5;
#pragma unroll
  for (int i = 0; i < 32; i += 8)
    tile[ty + i][tx] =
        V[(size_t)(b * 2048 + t0 + ty + i) * 6144 + kvh * 128 + d0 + tx];
  __syncthreads();
#pragma unroll
  for (int i = 0; i < 32; i += 8)
    VT[((size_t)s * 128 + d0 + ty + i) * 2048 + t0 + tx] = tile[tx][ty + i];
}

// ---------------------------------------------------------------- RoPE
__global__ void rope_table_k(float* __restrict__ tab) {
  int idx = blockIdx.x * 256 + threadIdx.x;  // t*64 + i
  int t = idx >> 6, i = idx & 63;
  float theta = powf(10000.0f, -2.0f * (float)i / 128.0f);
  float ang = (float)t * theta;
  tab[idx * 2 + 0] = cosf(ang);
  tab[idx * 2 + 1] = sinf(ang);
}

__global__ void rope_apply(bf16* __restrict__ X, const float* __restrict__ tab,
                           int nheads, int rowstride, float omul) {
  size_t idx = (size_t)blockIdx.x * 256 + threadIdx.x;
  int i = (int)(idx & 63);
  size_t rest = idx >> 6;
  int h = (int)(rest % nheads);
  size_t r = rest / nheads;
  int t = (int)(r & 2047);
  float c = tab[(t * 64 + i) * 2 + 0];
  float s = tab[(t * 64 + i) * 2 + 1];
  bf16* p = X + r * (size_t)rowstride + h * 128 + 2 * i;
  float xr = __bfloat162float(p[0]), xi = __bfloat162float(p[1]);
  p[0] = __float2bfloat16((xr * c - xi * s) * omul);
  p[1] = __float2bfloat16((xr * s + xi * c) * omul);
}

// ------------------------------------------------ GEMM 8-phase 256x256 BK=64
// C[M][N] = A[M][K] * BT[N][K]^T ; M,N % 256 == 0, K % 128 == 0.
// 8 waves (2M x 4N), per-wave 128x64 out, acc[8][4]. Phase = 2m x 4n x 2kk
// = 16 MFMA. B-frags read once/K-tile (q0), held in regs; A-pairs per phase.
// Double-buffered A,B (128 KB); counted vmcnt(4) at p3/p7 ONLY (T3+T4);
// chunk-XOR swizzle both sides (T2); setprio around MFMA (T5).
template <typename OutT>
__global__ __launch_bounds__(512, 2) void gemm_bt8(const bf16* __restrict__ A,
                                                   const bf16* __restrict__ BT,
                                                   OutT* __restrict__ C, int M,
                                                   int N, int K) {
  __shared__ bf16 AS[2][2][128 * 64];  // [buf][half][row*64 + swz-col]
  __shared__ bf16 BS[2][2][128 * 64];

  const int tid = threadIdx.x;
  const int lane = tid & 63;
  const int w = tid >> 6, wm = w >> 2, wn = w & 3;
  const int lr = lane & 15, hi = lane >> 4;

  // bijective XCD-chunked swizzle (grid % 8 == 0 for our shapes)
  int gx = gridDim.x;
  int nwg = gx * gridDim.y;
  int bid = blockIdx.y * gx + blockIdx.x;
  int swz = (bid & 7) * (nwg >> 3) + (bid >> 3);
  const int m0 = (swz / gx) * 256, n0 = (swz % gx) * 256;

  const int NKT = K >> 6;           // K-tiles of 64
  const int NI = K >> 7;            // iterations (2 K-tiles each)
  const int srow = tid >> 3;        // 0..63: row within 64-row strip
  const int scol = ((tid & 7) ^ (srow & 7)) << 3;  // swizzled source col (elems)

  f32x4 acc[8][4];
#pragma unroll
  for (int m = 0; m < 8; ++m)
#pragma unroll
    for (int n = 0; n < 4; ++n)
#pragma unroll
      for (int j = 0; j < 4; ++j) acc[m][n][j] = 0.f;

  // ---- staging: 4 A-strips (one K-tile) or 2 B-strips (one half pair)
  auto STAGE_A = [&](int buf, int kt) {
    int kk0 = (kt < NKT) ? kt * 64 : 0;  // tail clamp (keeps vmcnt counts)
#pragma unroll
    for (int hs = 0; hs < 4; ++hs) {
      int ha = hs >> 1, sa = hs & 1;
      const bf16* g = A + (size_t)(m0 + ha * 128 + sa * 64 + srow) * K + kk0 + scol;
      GLD16(g, &AS[buf][ha][(sa * 64 + srow) * 64 + (tid & 7) * 8]);
    }
  };
  auto STAGE_B = [&](int buf, int kt, int half) {
    int kk0 = (kt < NKT) ? kt * 64 : 0;
#pragma unroll
    for (int sa = 0; sa < 2; ++sa) {
      const bf16* g =
          BT + (size_t)(n0 + half * 128 + sa * 64 + srow) * K + kk0 + scol;
      GLD16(g, &BS[buf][half][(sa * 64 + srow) * 64 + (tid & 7) * 8]);
    }
  };

  // ---- fragment reads (swizzled)
  bf16x8 bfr[4][2], af[2][2];
  auto READ_B = [&](int buf) {
#pragma unroll
    for (int n = 0; n < 4; ++n) {
      int row = (wn & 1) * 64 + n * 16 + lr;
#pragma unroll
      for (int kk = 0; kk < 2; ++kk)
        bfr[n][kk] = *(const bf16x8*)(&BS[buf][wn >> 1]
                                         [row * 64 + (((kk * 4 + hi) ^ (row & 7)) << 3)]);
    }
  };
  auto READ_A = [&](int buf, int q) {
#pragma unroll
    for (int mm = 0; mm < 2; ++mm) {
      int row = (q * 2 + mm) * 16 + lr;
#pragma unroll
      for (int kk = 0; kk < 2; ++kk)
        af[mm][kk] = *(const bf16x8*)(&AS[buf][wm]
                                         [row * 64 + (((kk * 4 + hi) ^ (row & 7)) << 3)]);
    }
  };

#define MFMA16(q)                                                              \
  do {                                                                         \
    __builtin_amdgcn_s_setprio(1);                                             \
    _Pragma("unroll") for (int mm = 0; mm < 2; ++mm)                           \
        _Pragma("unroll") for (int n = 0; n < 4; ++n)                          \
        _Pragma("unroll") for (int kk = 0; kk < 2; ++kk)                       \
            acc[(q) * 2 + mm][n] = __builtin_amdgcn_mfma_f32_16x16x32_bf16(    \
                af[mm][kk], bfr[n][kk], acc[(q) * 2 + mm][n], 0, 0, 0);        \
    __builtin_amdgcn_s_setprio(0);                                             \
  } while (0)

  // ---- prologue: A(0), B(0), B(1); oldest 8 loads (A0,B0) must land
  STAGE_A(0, 0);
  STAGE_B(0, 0, 0);
  STAGE_B(0, 0, 1);
  STAGE_B(1, 1, 0);
  STAGE_B(1, 1, 1);
  VMCNT(4);
  BARRIER();

  for (int i = 0; i < NI; ++i) {
    int t = 2 * i;
    // ---- K-tile t (buf 0), phases 0-3
    READ_B(0); READ_A(0, 0); STAGE_A(1, t + 1);   // p0: 12 ds_read + 4 loads
    BARRIER(); MFMA16(0); BARRIER();
    READ_A(0, 1); STAGE_B(0, t + 2, 0);           // p1
    BARRIER(); MFMA16(1); BARRIER();
    READ_A(0, 2); STAGE_B(0, t + 2, 1);           // p2
    BARRIER(); MFMA16(2); BARRIER();
    READ_A(0, 3);                                 // p3
    BARRIER(); MFMA16(3); VMCNT(4); BARRIER();
    // ---- K-tile t+1 (buf 1), phases 4-7
    READ_B(1); READ_A(1, 0); STAGE_A(0, t + 2);   // p4
    BARRIER(); MFMA16(0); BARRIER();
    READ_A(1, 1); STAGE_B(1, t + 3, 0);           // p5
    BARRIER(); MFMA16(1); BARRIER();
    READ_A(1, 2); STAGE_B(1, t + 3, 1);           // p6
    BARRIER(); MFMA16(2); BARRIER();
    READ_A(1, 3);                                 // p7
    BARRIER(); MFMA16(3); VMCNT(4); BARRIER();
  }

  VMCNT(0);  // drain tail prefetches before LDS teardown
  BARRIER();

#pragma unroll
  for (int m = 0; m < 8; ++m) {
    int row_base = m0 + wm * 128 + m * 16 + hi * 4;
#pragma unroll
    for (int n = 0; n < 4; ++n) {
      int col = n0 + wn * 64 + n * 16 + lr;
#pragma unroll
      for (int j = 0; j < 4; ++j) {
        float v = acc[m][n][j];
        if constexpr (sizeof(OutT) == 2)
          C[(size_t)(row_base + j) * N + col] = (OutT)__float2bfloat16(v);
        else
          C[(size_t)(row_base + j) * N + col] = (OutT)v;
      }
    }
  }
#undef MFMA16
}

// ---------------------------------------------------------------- flash attn
// (unchanged from round 6: swapped QK/PV, reg-P via cvt_pk+shfl, exp2,
//  defer-max, setprio, XCD swizzle)
static __device__ inline u32 cvtpk_bf16(float a, float b) {
  u32 r;
  asm("v_cvt_pk_bf16_f32 %0, %1, %2" : "=v"(r) : "v"(a), "v"(b));
  return r;
}

__global__ __launch_bounds__(256) void flash_attn2(const bf16* __restrict__ Q,
                                                   const bf16* __restrict__ K,
                                                   const bf16* __restrict__ VT,
                                                   bf16* __restrict__ AO) {
  __shared__ bf16 Kbuf[2][64 * 128];
  __shared__ bf16 Vbuf[2][128 * 64];

  int bid = blockIdx.x;
  int lid = (bid & 7) * 128 + (bid >> 3);
  int qt = 15 - (lid & 15);
  int hq = (lid >> 4) & 3;
  int kvh = (lid >> 6) & 7;
  int b = lid >> 9;
  int h = kvh * 4 + hq;

  const int tid = threadIdx.x;
  const int lane = tid & 63, w = tid >> 6;
  const int lr = lane & 15, hi = lane >> 4;
  const int ko = hi * 8;
  const int qrow0 = qt * 128 + w * 32;
  const int nt = 2 * qt + 2;

  const bf16* Kg0 = K + (size_t)b * 2048 * 6144 + kvh * 128;
  const bf16* Vg0 = VT + (size_t)(b * 8 + kvh) * 128 * 2048;

  bf16x8 qf[2][4];
#pragma unroll
  for (int mi = 0; mi < 2; ++mi) {
    const bf16* qb = Q + (size_t)(b * 2048 + qrow0 + mi * 16 + lr) * 6144 + h * 128;
#pragma unroll
    for (int kk = 0; kk < 4; ++kk) qf[mi][kk] = *(const bf16x8*)(qb + kk * 32 + ko);
  }

  f32x4 O[2][8];
  float m_[2], l_[2];
#pragma unroll
  for (int mi = 0; mi < 2; ++mi) {
    m_[mi] = -1e30f;
    l_[mi] = 0.f;
#pragma unroll
    for (int dd = 0; dd < 8; ++dd)
#pragma unroll
      for (int j = 0; j < 4; ++j) O[mi][dd][j] = 0.f;
  }

  auto STAGE = [&](int buf, int kv0) {
    bf16* Ks = &Kbuf[buf][0];
    bf16* Vs = &Vbuf[buf][0];
    const bf16* Kg = Kg0 + (size_t)kv0 * 6144;
    const bf16* Vg = Vg0 + kv0;
#pragma unroll
    for (int it = 0; it < 4; ++it) {
      int s = it * 256 + tid;
      int row = s >> 4, c = s & 15;
      GLD16(Kg + (size_t)row * 6144 + ((c ^ (row & 7)) << 3), Ks + s * 8);
    }
#pragma unroll
    for (int it = 0; it < 4; ++it) {
      int s = it * 256 + tid;
      int row = s >> 3, c = s & 7;
      GLD16(Vg + (size_t)row * 2048 + ((c ^ (row & 7)) << 3), Vs + s * 8);
    }
  };

  STAGE(0, 0);
  __syncthreads();

  for (int t = 0; t < nt; ++t) {
    int kv0 = t * 64;
    if (t + 1 < nt) STAGE((t + 1) & 1, kv0 + 64);

    if (kv0 <= qrow0 + 31) {
      const bf16* Ks = &Kbuf[t & 1][0];
      const bf16* Vs = &Vbuf[t & 1][0];

      f32x4 Sx[2][4];
#pragma unroll
      for (int mi = 0; mi < 2; ++mi)
#pragma unroll
        for (int cb = 0; cb < 4; ++cb)
#pragma unroll
          for (int j = 0; j < 4; ++j) Sx[mi][cb][j] = 0.f;

      __builtin_amdgcn_s_setprio(1);
#pragma unroll
      for (int cb = 0; cb < 4; ++cb) {
        bf16x8 kf[4];
#pragma unroll
        for (int kk = 0; kk < 4; ++kk)
          kf[kk] = *(const bf16x8*)(Ks + (cb * 16 + lr) * 128 +
                                    (((kk * 4 + hi) ^ (lr & 7)) << 3));
#pragma unroll
        for (int mi = 0; mi < 2; ++mi)
#pragma unroll
          for (int kk = 0; kk < 4; ++kk)
            Sx[mi][cb] = __builtin_amdgcn_mfma_f32_16x16x32_bf16(
                kf[kk], qf[mi][kk], Sx[mi][cb], 0, 0, 0);
      }
      __builtin_amdgcn_s_setprio(0);

      bool domask = (kv0 + 63 > qrow0);
      u32 pau[2][2][4];
#pragma unroll
      for (int mi = 0; mi < 2; ++mi) {
        int q = qrow0 + mi * 16 + lr;
        if (domask) {
#pragma unroll
          for (int cb = 0; cb < 4; ++cb)
#pragma unroll
            for (int j = 0; j < 4; ++j)
              if (kv0 + cb * 16 + hi * 4 + j > q) Sx[mi][cb][j] = -1e30f;
        }
        float pm = -1e30f;
#pragma unroll
        for (int cb = 0; cb < 4; ++cb)
#pragma unroll
          for (int j = 0; j < 4; ++j) pm = fmaxf(pm, Sx[mi][cb][j]);
        pm = fmaxf(pm, __shfl_xor(pm, 16));
        pm = fmaxf(pm, __shfl_xor(pm, 32));

        if (!__all(pm - m_[mi] <= 11.5416f)) {
          float nm = fmaxf(m_[mi], pm);
          float rs = exp2f(m_[mi] - nm);
          m_[mi] = nm;
          l_[mi] *= rs;
#pragma unroll
          for (int dd = 0; dd < 8; ++dd)
#pragma unroll
            for (int j = 0; j < 4; ++j) O[mi][dd][j] *= rs;
        }
        float mcur = m_[mi];
        float ps = 0.f;
#pragma unroll
        for (int cb = 0; cb < 4; ++cb)
#pragma unroll
          for (int j = 0; j < 4; ++j) {
            float p = exp2f(Sx[mi][cb][j] - mcur);
            Sx[mi][cb][j] = p;
            ps += p;
          }
        ps += __shfl_xor(ps, 16);
        ps += __shfl_xor(ps, 32);
        l_[mi] += ps;

        u32 vp[8];
#pragma unroll
        for (int cb = 0; cb < 4; ++cb)
#pragma unroll
          for (int jp = 0; jp < 2; ++jp)
            vp[cb * 2 + jp] = cvtpk_bf16(Sx[mi][cb][2 * jp], Sx[mi][cb][2 * jp + 1]);

#pragma unroll
        for (int kk2 = 0; kk2 < 2; ++kk2)
#pragma unroll
          for (int e = 0; e < 4; ++e) {
            int src = lr + ((hi & 1) << 5) + ((e >> 1) << 4);
            u32 va = (u32)__shfl((int)vp[4 * kk2 + (e & 1)], src);
            u32 vb = (u32)__shfl((int)vp[4 * kk2 + 2 + (e & 1)], src);
            pau[mi][kk2][e] = (hi & 2) ? vb : va;
          }
      }

      __builtin_amdgcn_s_setprio(1);
#pragma unroll
      for (int dd = 0; dd < 8; ++dd) {
        bf16x8 vf[2];
#pragma unroll
        for (int kk2 = 0; kk2 < 2; ++kk2)
          vf[kk2] = *(const bf16x8*)(Vs + (dd * 16 + lr) * 64 +
                                     (((kk2 * 4 + hi) ^ (lr & 7)) << 3));
#pragma unroll
        for (int mi = 0; mi < 2; ++mi)
#pragma unroll
          for (int kk2 = 0; kk2 < 2; ++kk2) {
            union { u32 u[4]; bf16x8 h; } cv;
#pragma unroll
            for (int e = 0; e < 4; ++e) cv.u[e] = pau[mi][kk2][e];
            O[mi][dd] = __builtin_amdgcn_mfma_f32_16x16x32_bf16(
                vf[kk2], cv.h, O[mi][dd], 0, 0, 0);
          }
      }
      __builtin_amdgcn_s_setprio(0);
    }
    __syncthreads();
  }

#pragma unroll
  for (int mi = 0; mi < 2; ++mi) {
    float inv = 1.0f / l_[mi];
    bf16* outp = AO + (size_t)(b * 2048 + qrow0 + mi * 16 + lr) * 4096 + h * 128;
#pragma unroll
    for (int dd = 0; dd < 8; ++dd) {
      union { u16 s[4]; unsigned long long v; } pk;
#pragma unroll
      for (int j = 0; j < 4; ++j)
        pk.s[j] = __bfloat16_as_ushort(__float2bfloat16(O[mi][dd][j] * inv));
      *(unsigned long long*)(outp + dd * 16 + hi * 4) = pk.v;
    }
  }
}

// ---------------------------------------------------------------- launch
extern "C" void kernel_launch(void* const* d_in, const int* in_sizes, int n_in,
                              void* d_out, int out_size, void* d_ws,
                              size_t ws_size, hipStream_t stream) {
  const float* x = (const float*)d_in[0];
  const float* wq = (const float*)d_in[1];
  const float* wk = (const float*)d_in[2];
  const float* wv = (const float*)d_in[3];
  const float* wo = (const float*)d_in[4];

  char* ws = (char*)d_ws;
  bf16* xb    = (bf16*)(ws + 0);           // 32 MB — reused as AOb
  bf16* WqkvT = (bf16*)(ws + 33554432);    // 48 MB (6144x4096)
  bf16* WoT   = (bf16*)(ws + 83886080);    // 32 MB
  bf16* QKV   = (bf16*)(ws + 117440512);   // 48 MB (4096x6144)
  bf16* VTb   = (bf16*)(ws + 167772160);   //  8 MB (16x128x2048)
  float* tab  = (float*)(ws + 176160768);  //  1 MB
  bf16* AOb   = xb;

  const float LOG2E = 1.4426950408889634f;
  const float ISQ = 0.08838834764831845f;  // 1/sqrt(128)

  convert_f32_bf16<<<16384, 256, 0, stream>>>(x, xb);
  transpose_f32_bf16<<<dim3(128, 128), 256, 0, stream>>>(wq, WqkvT, 4096, 4096);
  transpose_f32_bf16<<<dim3(32, 128), 256, 0, stream>>>(
      wk, WqkvT + (size_t)4096 * 4096, 4096, 1024);
  transpose_f32_bf16<<<dim3(32, 128), 256, 0, stream>>>(
      wv, WqkvT + (size_t)5120 * 4096, 4096, 1024);
  transpose_f32_bf16<<<dim3(128, 128), 256, 0, stream>>>(wo, WoT, 4096, 4096);
  rope_table_k<<<512, 256, 0, stream>>>(tab);

  // fused QKV projection: [4096][4096] x [6144][4096]^T -> [4096][6144]
  gemm_bt8<bf16><<<dim3(24, 16), 512, 0, stream>>>(xb, WqkvT, QKV, 4096, 6144,
                                                   4096);

  rope_apply<<<32768, 256, 0, stream>>>(QKV, tab, 32, 6144, LOG2E * ISQ);
  rope_apply<<<8192, 256, 0, stream>>>(QKV + 4096, tab, 8, 6144, 1.0f);

  transpose_v<<<dim3(64, 4, 16), 256, 0, stream>>>(QKV + 5120, VTb);

  flash_attn2<<<1024, 256, 0, stream>>>(QKV, QKV + 4096, VTb, AOb);

  gemm_bt8<float><<<dim3(16, 16), 512, 0, stream>>>(AOb, WoT, (float*)d_out,
                                                    4096, 4096, 4096);
}

// Round 8
// 619.030 us; speedup vs baseline: 1.3334x; 1.0776x over previous
//
#include <hip/hip_runtime.h>
#include <hip/hip_bf16.h>
#include <math.h>

typedef __hip_bfloat16 bf16;
typedef short bf16x8 __attribute__((ext_vector_type(8)));
typedef float f32x4 __attribute__((ext_vector_type(4)));
typedef float f32x16 __attribute__((ext_vector_type(16)));
typedef unsigned int u32;
typedef unsigned short u16;

#define GLD16(g, l)                                                            \
  __builtin_amdgcn_global_load_lds(                                            \
      (const __attribute__((address_space(1))) void*)(g),                      \
      (__attribute__((address_space(3))) void*)(l), 16, 0, 0)

#define BARRIER() asm volatile("s_barrier" ::: "memory")
#define VMCNT(n) asm volatile("s_waitcnt vmcnt(" #n ")" ::: "memory")

// ------------------------------------------------------- f32 -> bf16 copy
__global__ void convert_f32_bf16(const float* __restrict__ in,
                                 bf16* __restrict__ out) {
  size_t i = ((size_t)blockIdx.x * 256 + threadIdx.x) * 4;
  float4 v = *(const float4*)(in + i);
  out[i + 0] = __float2bfloat16(v.x);
  out[i + 1] = __float2bfloat16(v.y);
  out[i + 2] = __float2bfloat16(v.z);
  out[i + 3] = __float2bfloat16(v.w);
}

// ----------------------------------------- f32 -> bf16 transposed weights
__global__ void transpose_f32_bf16(const float* __restrict__ in,
                                   bf16* __restrict__ out, int R, int C) {
  __shared__ bf16 tile[32][33];
  int tx = threadIdx.x & 31, ty = threadIdx.x >> 5;
  int c0 = blockIdx.x * 32, r0 = blockIdx.y * 32;
#pragma unroll
  for (int i = 0; i < 32; i += 8)
    tile[ty + i][tx] = __float2bfloat16(in[(size_t)(r0 + ty + i) * C + c0 + tx]);
  __syncthreads();
#pragma unroll
  for (int i = 0; i < 32; i += 8)
    out[(size_t)(c0 + ty + i) * R + r0 + tx] = tile[tx][ty + i];
}

// V block of QKV: [4096][6144] -> VT: [16][128][2048]
__global__ void transpose_v(const bf16* __restrict__ V, bf16* __restrict__ VT) {
  __shared__ bf16 tile[32][33];
  int s = blockIdx.z, b = s >> 3, kvh = s & 7;
  int t0 = blockIdx.x * 32, d0 = blockIdx.y * 32;
  int tx = threadIdx.x & 31, ty = threadIdx.x >> 5;
#pragma unroll
  for (int i = 0; i < 32; i += 8)
    tile[ty + i][tx] =
        V[(size_t)(b * 2048 + t0 + ty + i) * 6144 + kvh * 128 + d0 + tx];
  __syncthreads();
#pragma unroll
  for (int i = 0; i < 32; i += 8)
    VT[((size_t)s * 128 + d0 + ty + i) * 2048 + t0 + tx] = tile[tx][ty + i];
}

// ---------------------------------------------------------------- RoPE
__global__ void rope_table_k(float* __restrict__ tab) {
  int idx = blockIdx.x * 256 + threadIdx.x;  // t*64 + i
  int t = idx >> 6, i = idx & 63;
  float theta = powf(10000.0f, -2.0f * (float)i / 128.0f);
  float ang = (float)t * theta;
  tab[idx * 2 + 0] = cosf(ang);
  tab[idx * 2 + 1] = sinf(ang);
}

__global__ void rope_apply(bf16* __restrict__ X, const float* __restrict__ tab,
                           int nheads, int rowstride, float omul) {
  size_t idx = (size_t)blockIdx.x * 256 + threadIdx.x;
  int i = (int)(idx & 63);
  size_t rest = idx >> 6;
  int h = (int)(rest % nheads);
  size_t r = rest / nheads;
  int t = (int)(r & 2047);
  float c = tab[(t * 64 + i) * 2 + 0];
  float s = tab[(t * 64 + i) * 2 + 1];
  bf16* p = X + r * (size_t)rowstride + h * 128 + 2 * i;
  float xr = __bfloat162float(p[0]), xi = __bfloat162float(p[1]);
  p[0] = __float2bfloat16((xr * c - xi * s) * omul);
  p[1] = __float2bfloat16((xr * s + xi * c) * omul);
}

// ------------------------------------------------ GEMM 8-phase 256x256 BK=64
// (unchanged from round 7 — verified 8-phase counted-vmcnt structure)
template <typename OutT>
__global__ __launch_bounds__(512, 2) void gemm_bt8(const bf16* __restrict__ A,
                                                   const bf16* __restrict__ BT,
                                                   OutT* __restrict__ C, int M,
                                                   int N, int K) {
  __shared__ bf16 AS[2][2][128 * 64];
  __shared__ bf16 BS[2][2][128 * 64];

  const int tid = threadIdx.x;
  const int lane = tid & 63;
  const int w = tid >> 6, wm = w >> 2, wn = w & 3;
  const int lr = lane & 15, hi = lane >> 4;

  int gx = gridDim.x;
  int nwg = gx * gridDim.y;
  int bid = blockIdx.y * gx + blockIdx.x;
  int swz = (bid & 7) * (nwg >> 3) + (bid >> 3);
  const int m0 = (swz / gx) * 256, n0 = (swz % gx) * 256;

  const int NKT = K >> 6;
  const int NI = K >> 7;
  const int srow = tid >> 3;
  const int scol = ((tid & 7) ^ (srow & 7)) << 3;

  f32x4 acc[8][4];
#pragma unroll
  for (int m = 0; m < 8; ++m)
#pragma unroll
    for (int n = 0; n < 4; ++n)
#pragma unroll
      for (int j = 0; j < 4; ++j) acc[m][n][j] = 0.f;

  auto STAGE_A = [&](int buf, int kt) {
    int kk0 = (kt < NKT) ? kt * 64 : 0;
#pragma unroll
    for (int hs = 0; hs < 4; ++hs) {
      int ha = hs >> 1, sa = hs & 1;
      const bf16* g = A + (size_t)(m0 + ha * 128 + sa * 64 + srow) * K + kk0 + scol;
      GLD16(g, &AS[buf][ha][(sa * 64 + srow) * 64 + (tid & 7) * 8]);
    }
  };
  auto STAGE_B = [&](int buf, int kt, int half) {
    int kk0 = (kt < NKT) ? kt * 64 : 0;
#pragma unroll
    for (int sa = 0; sa < 2; ++sa) {
      const bf16* g =
          BT + (size_t)(n0 + half * 128 + sa * 64 + srow) * K + kk0 + scol;
      GLD16(g, &BS[buf][half][(sa * 64 + srow) * 64 + (tid & 7) * 8]);
    }
  };

  bf16x8 bfr[4][2], af[2][2];
  auto READ_B = [&](int buf) {
#pragma unroll
    for (int n = 0; n < 4; ++n) {
      int row = (wn & 1) * 64 + n * 16 + lr;
#pragma unroll
      for (int kk = 0; kk < 2; ++kk)
        bfr[n][kk] = *(const bf16x8*)(&BS[buf][wn >> 1]
                                         [row * 64 + (((kk * 4 + hi) ^ (row & 7)) << 3)]);
    }
  };
  auto READ_A = [&](int buf, int q) {
#pragma unroll
    for (int mm = 0; mm < 2; ++mm) {
      int row = (q * 2 + mm) * 16 + lr;
#pragma unroll
      for (int kk = 0; kk < 2; ++kk)
        af[mm][kk] = *(const bf16x8*)(&AS[buf][wm]
                                         [row * 64 + (((kk * 4 + hi) ^ (row & 7)) << 3)]);
    }
  };

#define MFMA16(q)                                                              \
  do {                                                                         \
    __builtin_amdgcn_s_setprio(1);                                             \
    _Pragma("unroll") for (int mm = 0; mm < 2; ++mm)                           \
        _Pragma("unroll") for (int n = 0; n < 4; ++n)                          \
        _Pragma("unroll") for (int kk = 0; kk < 2; ++kk)                       \
            acc[(q) * 2 + mm][n] = __builtin_amdgcn_mfma_f32_16x16x32_bf16(    \
                af[mm][kk], bfr[n][kk], acc[(q) * 2 + mm][n], 0, 0, 0);        \
    __builtin_amdgcn_s_setprio(0);                                             \
  } while (0)

  STAGE_A(0, 0);
  STAGE_B(0, 0, 0);
  STAGE_B(0, 0, 1);
  STAGE_B(1, 1, 0);
  STAGE_B(1, 1, 1);
  VMCNT(4);
  BARRIER();

  for (int i = 0; i < NI; ++i) {
    int t = 2 * i;
    READ_B(0); READ_A(0, 0); STAGE_A(1, t + 1);
    BARRIER(); MFMA16(0); BARRIER();
    READ_A(0, 1); STAGE_B(0, t + 2, 0);
    BARRIER(); MFMA16(1); BARRIER();
    READ_A(0, 2); STAGE_B(0, t + 2, 1);
    BARRIER(); MFMA16(2); BARRIER();
    READ_A(0, 3);
    BARRIER(); MFMA16(3); VMCNT(4); BARRIER();
    READ_B(1); READ_A(1, 0); STAGE_A(0, t + 2);
    BARRIER(); MFMA16(0); BARRIER();
    READ_A(1, 1); STAGE_B(1, t + 3, 0);
    BARRIER(); MFMA16(1); BARRIER();
    READ_A(1, 2); STAGE_B(1, t + 3, 1);
    BARRIER(); MFMA16(2); BARRIER();
    READ_A(1, 3);
    BARRIER(); MFMA16(3); VMCNT(4); BARRIER();
  }

  VMCNT(0);
  BARRIER();

#pragma unroll
  for (int m = 0; m < 8; ++m) {
    int row_base = m0 + wm * 128 + m * 16 + hi * 4;
#pragma unroll
    for (int n = 0; n < 4; ++n) {
      int col = n0 + wn * 64 + n * 16 + lr;
#pragma unroll
      for (int j = 0; j < 4; ++j) {
        float v = acc[m][n][j];
        if constexpr (sizeof(OutT) == 2)
          C[(size_t)(row_base + j) * N + col] = (OutT)__float2bfloat16(v);
        else
          C[(size_t)(row_base + j) * N + col] = (OutT)v;
      }
    }
  }
#undef MFMA16
}

// ---------------------------------------------------------------- flash attn v3
// 8 waves x 32 q-rows (256 q/block), mfma_32x32x16, KVBLK=64, dbuf LDS K/VT
// (XOR-swizzled, global_load_lds). Swapped QK^T and PV; P-row fully in-lane
// (split across lane/lane+32) -> exchange = 16 cvt_pk + 16 shfl_xor(32) + sel.
// Q pre-scaled by log2e/sqrt(d) -> exp2 softmax; defer-max; setprio.
// S^T layout (32x32 C-frag, m74/m101): col q = lane&31,
//   kv = (reg&3) + 8*(reg>>2) + 4*(lane>>5) (+ cb*32).
static __device__ inline u32 cvtpk_bf16(float a, float b) {
  u32 r;
  asm("v_cvt_pk_bf16_f32 %0, %1, %2" : "=v"(r) : "v"(a), "v"(b));
  return r;
}

__global__ __launch_bounds__(512) void flash_attn3(const bf16* __restrict__ Q,
                                                   const bf16* __restrict__ K,
                                                   const bf16* __restrict__ VT,
                                                   bf16* __restrict__ AO) {
  __shared__ bf16 Kbuf[2][64 * 128];  // [kv][d], swizzled chunks
  __shared__ bf16 Vbuf[2][128 * 64];  // [d][kv], swizzled chunks

  // decode: bid = kvh + 8*(hq*8 + (7-qt)) + 256*b  -> same (b,kvh) on one XCD
  int bid = blockIdx.x;
  int b = bid >> 8;
  int i = (bid >> 3) & 31;
  int kvh = bid & 7;
  int hq = i >> 3;
  int qt = 7 - (i & 7);
  int h = kvh * 4 + hq;

  const int tid = threadIdx.x;
  const int lane = tid & 63, w = tid >> 6;
  const int ql = lane & 31, hi = lane >> 5;
  const int qrow0 = qt * 256 + w * 32;
  const int nt = 4 * qt + 4;

  const bf16* Kg0 = K + (size_t)b * 2048 * 6144 + kvh * 128;
  const bf16* Vg0 = VT + (size_t)(b * 8 + kvh) * 128 * 2048;

  // Q fragments (B-operand): lane holds q-row qrow0+ql, d = dc*16 + hi*8 ..+8
  bf16x8 qf[8];
  {
    const bf16* qb =
        Q + (size_t)(b * 2048 + qrow0 + ql) * 6144 + h * 128 + hi * 8;
#pragma unroll
    for (int dc = 0; dc < 8; ++dc) qf[dc] = *(const bf16x8*)(qb + dc * 16);
  }

  f32x16 O[4];
#pragma unroll
  for (int d4 = 0; d4 < 4; ++d4)
#pragma unroll
    for (int e = 0; e < 16; ++e) O[d4][e] = 0.f;
  float m_ = -1e30f, l_ = 0.f;

  auto STAGE = [&](int buf, int kv0) {
    bf16* Ks = &Kbuf[buf][0];
    bf16* Vs = &Vbuf[buf][0];
    const bf16* Kg = Kg0 + (size_t)kv0 * 6144;
    const bf16* Vg = Vg0 + kv0;
#pragma unroll
    for (int it = 0; it < 2; ++it) {  // K: 64 rows x 16 chunks of 16B
      int s = it * 512 + tid;
      int row = s >> 4, c = s & 15;
      GLD16(Kg + (size_t)row * 6144 + ((c ^ (row & 7)) << 3), Ks + s * 8);
    }
#pragma unroll
    for (int it = 0; it < 2; ++it) {  // VT: 128 rows x 8 chunks of 16B
      int s = it * 512 + tid;
      int row = s >> 3, c = s & 7;
      GLD16(Vg + (size_t)row * 2048 + ((c ^ (row & 7)) << 3), Vs + s * 8);
    }
  };

  STAGE(0, 0);
  __syncthreads();

  for (int t = 0; t < nt; ++t) {
    int kv0 = t * 64;
    if (t + 1 < nt) STAGE((t + 1) & 1, kv0 + 64);

    if (kv0 <= qrow0 + 31) {
      const bf16* Ks = &Kbuf[t & 1][0];
      const bf16* Vs = &Vbuf[t & 1][0];

      // ---- S^T = K . Q^T : 2 cb-blocks x 8 d-chunks of mfma_32x32x16
      f32x16 Sx[2];
#pragma unroll
      for (int cb = 0; cb < 2; ++cb)
#pragma unroll
        for (int e = 0; e < 16; ++e) Sx[cb][e] = 0.f;

      __builtin_amdgcn_s_setprio(1);
#pragma unroll
      for (int cb = 0; cb < 2; ++cb) {
        int krow = cb * 32 + ql;
#pragma unroll
        for (int dc = 0; dc < 8; ++dc) {
          bf16x8 kf = *(const bf16x8*)(Ks + krow * 128 +
                                       (((dc * 2 + hi) ^ (ql & 7)) << 3));
          Sx[cb] = __builtin_amdgcn_mfma_f32_32x32x16_bf16(kf, qf[dc], Sx[cb],
                                                           0, 0, 0);
        }
      }
      __builtin_amdgcn_s_setprio(0);

      // ---- softmax (exp2 domain; scale folded into Q)
      int q = qrow0 + ql;
      bool domask = (kv0 + 63 > qrow0);
      if (domask) {
#pragma unroll
        for (int cb = 0; cb < 2; ++cb)
#pragma unroll
          for (int r = 0; r < 16; ++r) {
            int kv = kv0 + cb * 32 + (r & 3) + 8 * (r >> 2) + 4 * hi;
            if (kv > q) Sx[cb][r] = -1e30f;
          }
      }
      float pm = -1e30f;
#pragma unroll
      for (int cb = 0; cb < 2; ++cb)
#pragma unroll
        for (int r = 0; r < 16; ++r) pm = fmaxf(pm, Sx[cb][r]);
      pm = fmaxf(pm, __shfl_xor(pm, 32));

      if (!__all(pm - m_ <= 11.5416f)) {  // defer-max (THR = 8*log2e)
        float nm = fmaxf(m_, pm);
        float rs = exp2f(m_ - nm);
        m_ = nm;
        l_ *= rs;
#pragma unroll
        for (int d4 = 0; d4 < 4; ++d4)
#pragma unroll
          for (int e = 0; e < 16; ++e) O[d4][e] *= rs;
      }
      float ps = 0.f;
#pragma unroll
      for (int cb = 0; cb < 2; ++cb)
#pragma unroll
        for (int r = 0; r < 16; ++r) {
          float p = exp2f(Sx[cb][r] - m_);
          Sx[cb][r] = p;
          ps += p;
        }
      ps += __shfl_xor(ps, 32);
      l_ += ps;

      // ---- P -> PV B-fragments: per kv-16 block kb: 4 cvt_pk + 4 shfl_xor(32)
      bf16x8 pb[4];
#pragma unroll
      for (int kb = 0; kb < 4; ++kb) {
        int cb = kb >> 1, r0 = 8 * (kb & 1);
        u32 Av = cvtpk_bf16(Sx[cb][r0 + 0], Sx[cb][r0 + 1]);
        u32 Bv = cvtpk_bf16(Sx[cb][r0 + 2], Sx[cb][r0 + 3]);
        u32 Cv = cvtpk_bf16(Sx[cb][r0 + 4], Sx[cb][r0 + 5]);
        u32 Dv = cvtpk_bf16(Sx[cb][r0 + 6], Sx[cb][r0 + 7]);
        u32 sA = (u32)__shfl_xor((int)Av, 32);
        u32 sB = (u32)__shfl_xor((int)Bv, 32);
        u32 sC = (u32)__shfl_xor((int)Cv, 32);
        u32 sD = (u32)__shfl_xor((int)Dv, 32);
        union { u32 u[4]; bf16x8 v; } pk;
        pk.u[0] = hi ? sC : Av;   // jj 0,1
        pk.u[1] = hi ? sD : Bv;   // jj 2,3
        pk.u[2] = hi ? Cv : sA;   // jj 4,5
        pk.u[3] = hi ? Dv : sB;   // jj 6,7
        pb[kb] = pk.v;
      }

      // ---- O^T += VT . P^T : 4 d-blocks x 4 kv-blocks
      __builtin_amdgcn_s_setprio(1);
#pragma unroll
      for (int d4 = 0; d4 < 4; ++d4) {
        int vrow = d4 * 32 + ql;
#pragma unroll
        for (int kb = 0; kb < 4; ++kb) {
          bf16x8 vf = *(const bf16x8*)(Vs + vrow * 64 +
                                       (((kb * 2 + hi) ^ (ql & 7)) << 3));
          O[d4] = __builtin_amdgcn_mfma_f32_32x32x16_bf16(vf, pb[kb], O[d4], 0,
                                                          0, 0);
        }
      }
      __builtin_amdgcn_s_setprio(0);
    }
    __syncthreads();
  }

  // epilogue: lane owns q = qrow0+ql; d = d4*32 + 8*rg + 4*hi + j
  float inv = 1.0f / l_;
  bf16* outp = AO + (size_t)(b * 2048 + qrow0 + ql) * 4096 + h * 128;
#pragma unroll
  for (int d4 = 0; d4 < 4; ++d4)
#pragma unroll
    for (int rg = 0; rg < 4; ++rg) {
      union { u16 s[4]; unsigned long long v; } pk;
#pragma unroll
      for (int j = 0; j < 4; ++j)
        pk.s[j] = __bfloat16_as_ushort(__float2bfloat16(O[d4][rg * 4 + j] * inv));
      *(unsigned long long*)(outp + d4 * 32 + rg * 8 + hi * 4) = pk.v;
    }
}

// ---------------------------------------------------------------- launch
extern "C" void kernel_launch(void* const* d_in, const int* in_sizes, int n_in,
                              void* d_out, int out_size, void* d_ws,
                              size_t ws_size, hipStream_t stream) {
  const float* x = (const float*)d_in[0];
  const float* wq = (const float*)d_in[1];
  const float* wk = (const float*)d_in[2];
  const float* wv = (const float*)d_in[3];
  const float* wo = (const float*)d_in[4];

  char* ws = (char*)d_ws;
  bf16* xb    = (bf16*)(ws + 0);           // 32 MB — reused as AOb
  bf16* WqkvT = (bf16*)(ws + 33554432);    // 48 MB (6144x4096)
  bf16* WoT   = (bf16*)(ws + 83886080);    // 32 MB
  bf16* QKV   = (bf16*)(ws + 117440512);   // 48 MB (4096x6144)
  bf16* VTb   = (bf16*)(ws + 167772160);   //  8 MB (16x128x2048)
  float* tab  = (float*)(ws + 176160768);  //  1 MB
  bf16* AOb   = xb;

  const float LOG2E = 1.4426950408889634f;
  const float ISQ = 0.08838834764831845f;  // 1/sqrt(128)

  convert_f32_bf16<<<16384, 256, 0, stream>>>(x, xb);
  transpose_f32_bf16<<<dim3(128, 128), 256, 0, stream>>>(wq, WqkvT, 4096, 4096);
  transpose_f32_bf16<<<dim3(32, 128), 256, 0, stream>>>(
      wk, WqkvT + (size_t)4096 * 4096, 4096, 1024);
  transpose_f32_bf16<<<dim3(32, 128), 256, 0, stream>>>(
      wv, WqkvT + (size_t)5120 * 4096, 4096, 1024);
  transpose_f32_bf16<<<dim3(128, 128), 256, 0, stream>>>(wo, WoT, 4096, 4096);
  rope_table_k<<<512, 256, 0, stream>>>(tab);

  // fused QKV projection: [4096][4096] x [6144][4096]^T -> [4096][6144]
  gemm_bt8<bf16><<<dim3(24, 16), 512, 0, stream>>>(xb, WqkvT, QKV, 4096, 6144,
                                                   4096);

  rope_apply<<<32768, 256, 0, stream>>>(QKV, tab, 32, 6144, LOG2E * ISQ);
  rope_apply<<<8192, 256, 0, stream>>>(QKV + 4096, tab, 8, 6144, 1.0f);

  transpose_v<<<dim3(64, 4, 16), 256, 0, stream>>>(QKV + 5120, VTb);

  flash_attn3<<<512, 512, 0, stream>>>(QKV, QKV + 4096, VTb, AOb);

  gemm_bt8<float><<<dim3(16, 16), 512, 0, stream>>>(AOb, WoT, (float*)d_out,
                                                    4096, 4096, 4096);
}